// Round 7
// baseline (89.735 us; speedup 1.0000x reference)
//
#include <hip/hip_runtime.h>

#define EMB 200
#define U_DIM 32
#define T_DIM 4
#define DIM_A 32
#define NN 10
#define NWAVE 4
#define BPW 4
#define NB (NWAVE * BPW)     // 16 b's per block
#define G 4                  // same-type b's per stage-2 group

__global__ __launch_bounds__(256, 4) void gatne(
    const int* __restrict__ train_inputs,
    const int* __restrict__ train_types,
    const int* __restrict__ node_neigh,
    const float* __restrict__ node_emb,
    const float* __restrict__ node_type_emb,
    const float* __restrict__ tw,
    const float* __restrict__ tw1,
    const float* __restrict__ tw2,
    float* __restrict__ out)
{
    __shared__ __align__(16) float s_nte[NWAVE][T_DIM][U_DIM];  // 2 KB
    __shared__ __align__(16) float s_comb[NB][U_DIM];           // 2 KB
    __shared__ int s_list[T_DIM][NB];
    __shared__ int s_node[NB];
    __shared__ int s_cnt[T_DIM];

    const int tid  = threadIdx.x;
    const int wid  = tid >> 6;
    const int lane = tid & 63;
    const int u    = lane & 31;
    const int th   = lane >> 5;
    const int base = blockIdx.x * NB;

    if (tid < T_DIM) s_cnt[tid] = 0;

    // ---- hoist neighbor indices + types (plenty of VGPR headroom) ----
    int nb[BPW], ty[BPW];
    #pragma unroll
    for (int i = 0; i < BPW; ++i) {
        const int b = base + i * NWAVE + wid;
        nb[i] = (lane < T_DIM * NN) ? node_neigh[b * T_DIM * NN + lane] : 0;
        ty[i] = train_types[b];
    }

    // gather staging, double-buffered; index select via readlane+cndmask (no DS)
    float g[2][2][NN];
    #pragma unroll
    for (int tt = 0; tt < 2; ++tt) {
        #pragma unroll
        for (int n = 0; n < NN; ++n) {
            const int i0 = __builtin_amdgcn_readlane(nb[0], (2 * tt) * NN + n);
            const int i1 = __builtin_amdgcn_readlane(nb[0], (2 * tt + 1) * NN + n);
            const int idx = th ? i1 : i0;
            g[0][tt][n] = node_type_emb[((long)idx * T_DIM + (2 * tt + th)) * U_DIM + u];
        }
    }
    __syncthreads();   // s_cnt init visible before stage-1 atomics

    // ================= stage 1: gather-sum + attention -> comb =================
    #pragma unroll
    for (int i = 0; i < BPW; ++i) {
        const int cb = i & 1, nx = cb ^ 1;
        const int b  = base + i * NWAVE + wid;
        const int lb = i * NWAVE + wid;
        const int type = ty[i];

        // consume staged gathers
        #pragma unroll
        for (int tt = 0; tt < 2; ++tt) {
            float a = 0.f;
            #pragma unroll
            for (int n = 0; n < NN; ++n) a += g[cb][tt][n];
            s_nte[wid][tt * 2 + th][u] = a;
        }

        // issue next b's gathers (indices register-resident; covered by attention)
        if (i + 1 < BPW) {
            #pragma unroll
            for (int tt = 0; tt < 2; ++tt) {
                #pragma unroll
                for (int n = 0; n < NN; ++n) {
                    const int i0 = __builtin_amdgcn_readlane(nb[i + 1], (2 * tt) * NN + n);
                    const int i1 = __builtin_amdgcn_readlane(nb[i + 1], (2 * tt + 1) * NN + n);
                    const int idx = th ? i1 : i0;
                    g[nx][tt][n] = node_type_emb[((long)idx * T_DIM + (2 * tt + th)) * U_DIM + u];
                }
            }
        }

        const int ndv = train_inputs[b];

        // attention: uniform float4 broadcasts from LDS (16 ops instead of 64)
        const float* tw1p = tw1 + type * U_DIM * DIM_A;
        const float  w2   = tw2[type * DIM_A + u];
        float sc[2];
        #pragma unroll
        for (int tt = 0; tt < 2; ++tt) {
            const int t = tt * 2 + th;
            float a1 = 0.f;
            #pragma unroll
            for (int q = 0; q < 8; ++q) {
                const float4 bc = *(const float4*)&s_nte[wid][t][q * 4];
                a1 += bc.x * tw1p[(q * 4 + 0) * DIM_A + u];
                a1 += bc.y * tw1p[(q * 4 + 1) * DIM_A + u];
                a1 += bc.z * tw1p[(q * 4 + 2) * DIM_A + u];
                a1 += bc.w * tw1p[(q * 4 + 3) * DIM_A + u];
            }
            float s = tanhf(a1) * w2;
            #pragma unroll
            for (int m = 1; m < 32; m <<= 1) s += __shfl_xor(s, m, 64);
            sc[tt] = s;
        }
        const float o0 = __shfl_xor(sc[0], 32, 64);
        const float o1 = __shfl_xor(sc[1], 32, 64);
        const float s0 = th ? o0    : sc[0];
        const float s1 = th ? sc[0] : o0;
        const float s2 = th ? o1    : sc[1];
        const float s3 = th ? sc[1] : o1;

        const float mx  = fmaxf(fmaxf(s0, s1), fmaxf(s2, s3));
        const float e0  = __expf(s0 - mx), e1 = __expf(s1 - mx);
        const float e2  = __expf(s2 - mx), e3 = __expf(s3 - mx);
        const float inv = 1.f / (e0 + e1 + e2 + e3);
        const float comb = (e0 * s_nte[wid][0][u] + e1 * s_nte[wid][1][u] +
                            e2 * s_nte[wid][2][u] + e3 * s_nte[wid][3][u]) * inv;
        if (lane < 32) s_comb[lb][u] = comb;
        if (lane == 0) {
            s_node[lb] = ndv;
            const int sl = atomicAdd(&s_cnt[type], 1);
            s_list[type][sl] = lb;
        }
    }
    __syncthreads();

    // ================= stage 2: type-grouped matvec (G=4 b's share tw reads) =================
    const int  c   = lane;
    const int  cc  = (c < EMB / 4 - 1) ? c : (EMB / 4 - 1);
    const bool act = c < EMB / 4;      // 50 active float4 chunks

    const int c0 = s_cnt[0], c1 = s_cnt[1], c2 = s_cnt[2], c3 = s_cnt[3];
    const int p0 = (c0 + G - 1) / G;
    const int p1 = p0 + (c1 + G - 1) / G;
    const int p2 = p1 + (c2 + G - 1) / G;
    const int gtot = p2 + (c3 + G - 1) / G;

    for (int gi = wid; gi < gtot; gi += NWAVE) {
        int t, off, cnt_t;
        if      (gi < p0) { t = 0; off = gi;      cnt_t = c0; }
        else if (gi < p1) { t = 1; off = gi - p0; cnt_t = c1; }
        else if (gi < p2) { t = 2; off = gi - p1; cnt_t = c2; }
        else              { t = 3; off = gi - p2; cnt_t = c3; }
        const int cb2 = off * G;
        const int n   = min(G, cnt_t - cb2);

        // cooperative comb read: lanes 0-31 hold all 4 b's x 32 comb values
        const int bsel = min((lane >> 3) & 3, n - 1);
        const int lbs  = s_list[t][cb2 + bsel];
        const float4 cr4 = *(const float4*)&s_comb[lbs][(lane & 7) * 4];
        const float crf[4] = {cr4.x, cr4.y, cr4.z, cr4.w};

        int lbk[G];
        #pragma unroll
        for (int k = 0; k < G; ++k) lbk[k] = s_list[t][cb2 + min(k, n - 1)];

        // prefetch node rows (latency hidden under the FMA loop)
        float4 nv[G];
        #pragma unroll
        for (int k = 0; k < G; ++k) {
            const int nd = s_node[lbk[k]];
            nv[k] = *(const float4*)(node_emb + (size_t)nd * EMB + cc * 4);
        }

        float4 acc[G];
        #pragma unroll
        for (int k = 0; k < G; ++k) acc[k] = make_float4(0.f, 0.f, 0.f, 0.f);

        const float* twp = tw + (size_t)t * U_DIM * EMB + cc * 4;
        #pragma unroll
        for (int uu = 0; uu < U_DIM; ++uu) {
            const float4 wv = *(const float4*)(twp + uu * EMB);
            #pragma unroll
            for (int k = 0; k < G; ++k) {
                const float cg = __int_as_float(__builtin_amdgcn_readlane(
                    __float_as_int(crf[uu & 3]), k * 8 + (uu >> 2)));
                acc[k].x += cg * wv.x; acc[k].y += cg * wv.y;
                acc[k].z += cg * wv.z; acc[k].w += cg * wv.w;
            }
        }

        #pragma unroll
        for (int k = 0; k < G; ++k) {
            const float vx = acc[k].x + nv[k].x, vy = acc[k].y + nv[k].y;
            const float vz = acc[k].z + nv[k].z, vw = acc[k].w + nv[k].w;
            float ss = act ? (vx * vx + vy * vy + vz * vz + vw * vw) : 0.f;
            #pragma unroll
            for (int m = 1; m < 64; m <<= 1) ss += __shfl_xor(ss, m, 64);
            const float rinv = 1.f / fmaxf(sqrtf(ss), 1e-12f);
            if (act && k < n) {
                float4 o = make_float4(vx * rinv, vy * rinv, vz * rinv, vw * rinv);
                *(float4*)(out + (size_t)(base + lbk[k]) * EMB + c * 4) = o;
            }
        }
    }
}

extern "C" void kernel_launch(void* const* d_in, const int* in_sizes, int n_in,
                              void* d_out, int out_size, void* d_ws, size_t ws_size,
                              hipStream_t stream) {
    const int*   train_inputs = (const int*)d_in[0];
    const int*   train_types  = (const int*)d_in[1];
    const int*   node_neigh   = (const int*)d_in[2];
    const float* node_emb     = (const float*)d_in[3];
    const float* node_type_e  = (const float*)d_in[4];
    const float* tw           = (const float*)d_in[5];
    const float* tw1          = (const float*)d_in[6];
    const float* tw2          = (const float*)d_in[7];
    float*       out          = (float*)d_out;

    const int B = in_sizes[0];        // 16384
    const int blocks = B / NB;        // 1024 blocks -> 4 blocks/CU, 16 waves/CU

    gatne<<<blocks, NWAVE * 64, 0, stream>>>(
        train_inputs, train_types, node_neigh,
        node_emb, node_type_e, tw, tw1, tw2, out);
}

// Round 8
// 35.845 us; speedup vs baseline: 2.5034x; 2.5034x over previous
//
#include <hip/hip_runtime.h>

#define EMB 200
#define U_DIM 32
#define T_DIM 4
#define DIM_A 32
#define NN 10
#define BLK 512
#define NWAVE 8
#define BPW 8
#define TW_FLOATS (T_DIM * U_DIM * EMB)   // 25600 floats = 102400 B

__device__ __forceinline__ float readlane_f(float v, int l) {
    return __int_as_float(__builtin_amdgcn_readlane(__float_as_int(v), l));
}

__global__ __launch_bounds__(BLK, 2) void gatne_fused(
    const int* __restrict__ train_inputs,
    const int* __restrict__ train_types,
    const int* __restrict__ node_neigh,
    const float* __restrict__ node_emb,
    const float* __restrict__ node_type_emb,
    const float* __restrict__ tw,
    const float* __restrict__ tw1,
    const float* __restrict__ tw2,
    float* __restrict__ out)
{
    __shared__ float s_tw[TW_FLOATS];                            // 102.4 KB
    __shared__ __align__(16) float s_nte[NWAVE][T_DIM][U_DIM];   // 4 KB

    const int wid  = threadIdx.x >> 6;
    const int lane = threadIdx.x & 63;
    const int u    = lane & 31;
    const int th   = lane >> 5;
    const int base = blockIdx.x * (NWAVE * BPW);

    // ---- hoist all index/type loads (24 VGPRs; cap is 256 at BLK=512) ----
    int nb[BPW], ty[BPW], nd[BPW];
    #pragma unroll
    for (int i = 0; i < BPW; ++i) {
        const int b = base + i * NWAVE + wid;
        nb[i] = (lane < T_DIM * NN) ? node_neigh[b * T_DIM * NN + lane] : 0;
        ty[i] = train_types[b];
        nd[i] = train_inputs[b];
    }

    // ---- stage all of tw into LDS (covers index-load latency) ----
    {
        const float4* src = (const float4*)tw;
        float4*       dst = (float4*)s_tw;
        #pragma unroll
        for (int k = 0; k < 13; ++k) {
            const int i = threadIdx.x + k * BLK;
            if (i < TW_FLOATS / 4) dst[i] = src[i];
        }
    }

    // gather staging registers, double-buffered across b's.
    // index select via readlane+cndmask: zero DS ops.
    float g[2][2][NN];
    #pragma unroll
    for (int tt = 0; tt < 2; ++tt) {
        #pragma unroll
        for (int n = 0; n < NN; ++n) {
            const int i0 = __builtin_amdgcn_readlane(nb[0], (2 * tt) * NN + n);
            const int i1 = __builtin_amdgcn_readlane(nb[0], (2 * tt + 1) * NN + n);
            const int idx = th ? i1 : i0;
            g[0][tt][n] = node_type_emb[((long)idx * T_DIM + (2 * tt + th)) * U_DIM + u];
        }
    }

    // prefetch b0's node-embedding row
    float4 nv_cur = make_float4(0.f, 0.f, 0.f, 0.f);
    if (lane < EMB / 4)
        nv_cur = *(const float4*)(node_emb + (size_t)nd[0] * EMB + lane * 4);

    __syncthreads();

    #pragma unroll
    for (int i = 0; i < BPW; ++i) {
        const int cb   = i & 1;
        const int nx   = cb ^ 1;
        const int b    = base + i * NWAVE + wid;
        const int type = ty[i];

        // consume staged gathers -> s_nte (per-wave slot, no barrier)
        #pragma unroll
        for (int tt = 0; tt < 2; ++tt) {
            float a0 = 0.f;
            #pragma unroll
            for (int n = 0; n < NN; ++n) a0 += g[cb][tt][n];
            s_nte[wid][tt * 2 + th][u] = a0;
        }

        // issue gathers for b_{i+1}: indices register-resident, select via
        // readlane (VALU) — loads fly under attention + matvec (T14)
        if (i + 1 < BPW) {
            #pragma unroll
            for (int tt = 0; tt < 2; ++tt) {
                #pragma unroll
                for (int n = 0; n < NN; ++n) {
                    const int i0 = __builtin_amdgcn_readlane(nb[i + 1], (2 * tt) * NN + n);
                    const int i1 = __builtin_amdgcn_readlane(nb[i + 1], (2 * tt + 1) * NN + n);
                    const int idx = th ? i1 : i0;
                    g[nx][tt][n] = node_type_emb[((long)idx * T_DIM + (2 * tt + th)) * U_DIM + u];
                }
            }
        }

        // prefetch next b's node row (consumed next iteration)
        float4 nv_next = make_float4(0.f, 0.f, 0.f, 0.f);
        if (i + 1 < BPW && lane < EMB / 4)
            nv_next = *(const float4*)(node_emb + (size_t)nd[i + 1] * EMB + lane * 4);

        // ---- attention: s_nte via uniform float4 broadcasts (16 DS ops, not 64) ----
        const float* tw1p = tw1 + type * U_DIM * DIM_A;
        const float  w2   = tw2[type * DIM_A + u];
        float sc[2];
        #pragma unroll
        for (int tt = 0; tt < 2; ++tt) {
            const int t = tt * 2 + th;
            float a1 = 0.f;
            #pragma unroll
            for (int q = 0; q < 8; ++q) {
                const float4 bc = *(const float4*)&s_nte[wid][t][q * 4];
                a1 += bc.x * tw1p[(q * 4 + 0) * DIM_A + u];
                a1 += bc.y * tw1p[(q * 4 + 1) * DIM_A + u];
                a1 += bc.z * tw1p[(q * 4 + 2) * DIM_A + u];
                a1 += bc.w * tw1p[(q * 4 + 3) * DIM_A + u];
            }
            float s = tanhf(a1) * w2;
            #pragma unroll
            for (int m = 1; m < 32; m <<= 1) s += __shfl_xor(s, m, 64);
            sc[tt] = s;
        }
        const float o0 = __shfl_xor(sc[0], 32, 64);
        const float o1 = __shfl_xor(sc[1], 32, 64);
        const float s0 = th ? o0    : sc[0];
        const float s1 = th ? sc[0] : o0;
        const float s2 = th ? o1    : sc[1];
        const float s3 = th ? sc[1] : o1;

        const float mx  = fmaxf(fmaxf(s0, s1), fmaxf(s2, s3));
        const float e0  = __expf(s0 - mx), e1 = __expf(s1 - mx);
        const float e2  = __expf(s2 - mx), e3 = __expf(s3 - mx);
        const float inv = 1.f / (e0 + e1 + e2 + e3);
        const float comb = (e0 * s_nte[wid][0][u] + e1 * s_nte[wid][1][u] +
                            e2 * s_nte[wid][2][u] + e3 * s_nte[wid][3][u]) * inv;
        // comb stays in registers; matvec broadcasts it via readlane (no s_comb)

        // ---- matvec from LDS-resident tw; comb scalar via readlane (SGPR) ----
        const float* twp = s_tw + type * U_DIM * EMB;
        float4 v = nv_cur;
        if (lane < EMB / 4) {
            #pragma unroll
            for (int uu = 0; uu < U_DIM; ++uu) {
                const float  cg = readlane_f(comb, uu);
                const float4 w  = *(const float4*)(twp + uu * EMB + lane * 4);
                v.x += cg * w.x; v.y += cg * w.y; v.z += cg * w.z; v.w += cg * w.w;
            }
        }
        float ss = (lane < EMB / 4) ? (v.x * v.x + v.y * v.y + v.z * v.z + v.w * v.w) : 0.f;
        #pragma unroll
        for (int m = 1; m < 64; m <<= 1) ss += __shfl_xor(ss, m, 64);
        const float rinv = 1.f / fmaxf(sqrtf(ss), 1e-12f);
        if (lane < EMB / 4) {
            float4 o = make_float4(v.x * rinv, v.y * rinv, v.z * rinv, v.w * rinv);
            *(float4*)(out + (size_t)b * EMB + lane * 4) = o;
        }
        nv_cur = nv_next;
    }
}

extern "C" void kernel_launch(void* const* d_in, const int* in_sizes, int n_in,
                              void* d_out, int out_size, void* d_ws, size_t ws_size,
                              hipStream_t stream) {
    const int*   train_inputs = (const int*)d_in[0];
    const int*   train_types  = (const int*)d_in[1];
    const int*   node_neigh   = (const int*)d_in[2];
    const float* node_emb     = (const float*)d_in[3];
    const float* node_type_e  = (const float*)d_in[4];
    const float* tw           = (const float*)d_in[5];
    const float* tw1          = (const float*)d_in[6];
    const float* tw2          = (const float*)d_in[7];
    float*       out          = (float*)d_out;

    const int B = in_sizes[0];                 // 16384
    const int blocks = B / (NWAVE * BPW);      // 256 — one block per CU

    gatne_fused<<<blocks, BLK, 0, stream>>>(
        train_inputs, train_types, node_neigh,
        node_emb, node_type_e, tw, tw1, tw2, out);
}